// Round 1
// baseline (111.875 us; speedup 1.0000x reference)
//
#include <hip/hip_runtime.h>
#include <hip/hip_bf16.h>

// Problem shape (fixed by setup_inputs): B=8, T=2048, C=1024, fp32.
// y[b,t,d] = v[b,1,d] where v = x @ W^T + bias  -> only t=1 rows of the GEMM
// are needed. Kernel 1: 8x1024 GEMV into d_ws. Kernel 2: broadcast-store 67MB.

#define B_  8
#define T_  2048
#define C_  1024

// One wave (64 lanes) per output element v1[b][d].
__global__ __launch_bounds__(256) void gemv_row1(
    const float* __restrict__ x, const float* __restrict__ W,
    const float* __restrict__ bias, float* __restrict__ v1) {
    const int wave = blockIdx.x * (blockDim.x >> 6) + (threadIdx.x >> 6);
    const int lane = threadIdx.x & 63;
    const int b = wave >> 10;        // / C_
    const int d = wave & (C_ - 1);   // % C_
    if (b >= B_) return;

    // x row at (b, t=1, :) ; W row d
    const float4* __restrict__ xr = reinterpret_cast<const float4*>(
        x + (size_t)b * T_ * C_ + C_);
    const float4* __restrict__ wr = reinterpret_cast<const float4*>(
        W + (size_t)d * C_);

    float sum = 0.f;
    // C_/4 = 256 float4 per row, 64 lanes -> 4 iterations, fully coalesced
    #pragma unroll
    for (int k = lane; k < C_ / 4; k += 64) {
        float4 a = xr[k];
        float4 w = wr[k];
        sum += a.x * w.x + a.y * w.y + a.z * w.z + a.w * w.w;
    }
    // 64-lane butterfly reduction
    #pragma unroll
    for (int off = 32; off > 0; off >>= 1)
        sum += __shfl_xor(sum, off, 64);

    if (lane == 0) v1[wave] = sum + bias[d];
}

// Broadcast v1[b,:] across all T rows. One float4 store per thread.
__global__ __launch_bounds__(256) void bcast_row(
    const float4* __restrict__ v4, float4* __restrict__ out4) {
    const int i = blockIdx.x * blockDim.x + threadIdx.x;
    // total float4 = B_*T_*C_/4 = 4,194,304 ; grid covers exactly this
    const int b  = i >> 19;          // / (T_*C_/4) = 524288 = 2^19
    const int d4 = i & 255;          // % (C_/4)
    out4[i] = v4[(b << 8) + d4];
}

extern "C" void kernel_launch(void* const* d_in, const int* in_sizes, int n_in,
                              void* d_out, int out_size, void* d_ws, size_t ws_size,
                              hipStream_t stream) {
    const float* x    = (const float*)d_in[0];
    const float* W    = (const float*)d_in[1];
    const float* bias = (const float*)d_in[2];
    float* out = (float*)d_out;
    float* v1  = (float*)d_ws;   // 8192 floats = 32 KB scratch

    // Kernel 1: 8192 waves, 4 waves/block -> 2048 blocks
    gemv_row1<<<(B_ * C_) / 4, 256, 0, stream>>>(x, W, bias, v1);

    // Kernel 2: 4,194,304 float4 / 256 threads = 16384 blocks
    const int total4 = B_ * T_ * C_ / 4;
    bcast_row<<<total4 / 256, 256, 0, stream>>>(
        (const float4*)v1, (float4*)out);
}

// Round 2
// 111.549 us; speedup vs baseline: 1.0029x; 1.0029x over previous
//
#include <hip/hip_runtime.h>
#include <hip/hip_bf16.h>

// Problem shape (fixed by setup_inputs): B=8, T=2048, C=1024, fp32.
// y[b,t,d] = v[b,1,d] where v = x @ W^T + bias  -> only the t=1 rows of the
// GEMM matter. Kernel 1: 8x1024 GEMV into d_ws. Kernel 2: broadcast 67MB.
// R2: fatter per-block work to amortize workgroup dispatch overhead.

#define B_  8
#define T_  2048
#define C_  1024

// Each wave computes 4 adjacent outputs v1[b][d0..d0+3], reusing the x-row
// chunk held in registers. 2048 waves total -> 512 blocks of 256.
__global__ __launch_bounds__(256) void gemv_row1(
    const float* __restrict__ x, const float* __restrict__ W,
    const float* __restrict__ bias, float* __restrict__ v1) {
    const int wave = blockIdx.x * (blockDim.x >> 6) + (threadIdx.x >> 6);
    const int lane = threadIdx.x & 63;
    const int b  = wave >> 8;            // wave / 256 ; 256 d-groups per b
    const int d0 = (wave & 255) << 2;    // 4 adjacent d per wave

    // x row at (b, t=1, :): lane covers k = lane + 64*i, i=0..3
    const float4* __restrict__ xr = reinterpret_cast<const float4*>(
        x + (size_t)b * T_ * C_ + C_);
    float4 xc[4];
    #pragma unroll
    for (int i = 0; i < 4; ++i) xc[i] = xr[lane + 64 * i];

    float sums[4];
    #pragma unroll
    for (int j = 0; j < 4; ++j) {
        const float4* __restrict__ wr = reinterpret_cast<const float4*>(
            W + (size_t)(d0 + j) * C_);
        float s = 0.f;
        #pragma unroll
        for (int i = 0; i < 4; ++i) {
            float4 w = wr[lane + 64 * i];
            s += xc[i].x * w.x + xc[i].y * w.y + xc[i].z * w.z + xc[i].w * w.w;
        }
        sums[j] = s;
    }
    // 64-lane butterfly reduction on 4 values
    #pragma unroll
    for (int off = 32; off > 0; off >>= 1) {
        #pragma unroll
        for (int j = 0; j < 4; ++j)
            sums[j] += __shfl_xor(sums[j], off, 64);
    }
    if (lane < 4) v1[b * C_ + d0 + lane] = sums[lane] + bias[d0 + lane];
    // note: lane i holds all sums; use lane<4 picking sums[lane] -- all lanes
    // have identical sums after butterfly, so sums[lane] is valid.
}

// Broadcast: 2^19 threads (2048 blocks x 256). Thread i: b = i>>16,
// t0 = (i>>8)&255, d4 = i&255. Reads its v float4 ONCE, stores it to rows
// t = t0 + 256*k, k=0..7. Wave stores 64 consecutive float4 = 1KB/iteration.
__global__ __launch_bounds__(256) void bcast_row(
    const float4* __restrict__ v4, float4* __restrict__ out4) {
    const int i  = blockIdx.x * blockDim.x + threadIdx.x;
    const int b  = i >> 16;
    const int t0 = (i >> 8) & 255;
    const int d4 = i & 255;
    const float4 val = v4[(b << 8) + d4];
    // out4 index: ((b*T + t) * 256) + d4 ; b*T*256 = b<<19
    const size_t base = ((size_t)b << 19) + ((size_t)t0 << 8) + d4;
    #pragma unroll
    for (int k = 0; k < 8; ++k) {
        out4[base + ((size_t)k << 16)] = val;   // t += 256 -> idx += 256*256
    }
}

extern "C" void kernel_launch(void* const* d_in, const int* in_sizes, int n_in,
                              void* d_out, int out_size, void* d_ws, size_t ws_size,
                              hipStream_t stream) {
    const float* x    = (const float*)d_in[0];
    const float* W    = (const float*)d_in[1];
    const float* bias = (const float*)d_in[2];
    float* out = (float*)d_out;
    float* v1  = (float*)d_ws;   // 8192 floats = 32 KB scratch

    // Kernel 1: 2048 waves (4 d each) -> 512 blocks of 256
    gemv_row1<<<512, 256, 0, stream>>>(x, W, bias, v1);

    // Kernel 2: 2^19 threads, 8 float4 stores each -> 2048 blocks of 256
    bcast_row<<<2048, 256, 0, stream>>>((const float4*)v1, (float4*)out);
}

// Round 3
// 109.210 us; speedup vs baseline: 1.0244x; 1.0214x over previous
//
#include <hip/hip_runtime.h>
#include <hip/hip_bf16.h>

// Problem shape (fixed by setup_inputs): B=8, T=2048, C=1024, fp32.
// y[b,t,d] = v[b,1,d] where v = x @ W^T + bias  -> only t=1 rows of the GEMM
// matter. R3: single fused kernel. 256 blocks; block = (b, 32-wide d-chunk).
// Phase 1: 32 dot-products (len 1024) into LDS. Phase 2: broadcast those 32
// floats across all 2048 t-rows (128B-contiguous float4 store groups).

#define B_  8
#define T_  2048
#define C_  1024

__global__ __launch_bounds__(256) void fused_target_attn(
    const float* __restrict__ x, const float* __restrict__ W,
    const float* __restrict__ bias, float* __restrict__ out) {
    __shared__ float v_s[32];

    const int bid = blockIdx.x;          // 0..255
    const int b   = bid >> 5;            // 8 batches
    const int d0  = (bid & 31) << 5;     // 32-float d-chunk

    const int tid = threadIdx.x;         // 0..255
    const int row = tid >> 3;            // 0..31  (which d within chunk)
    const int sub = tid & 7;             // 8 threads per row

    // ---- Phase 1: v_s[row] = dot(x[b,1,:], W[d0+row,:]) + bias ----
    const float4* __restrict__ xr = reinterpret_cast<const float4*>(
        x + (size_t)b * T_ * C_ + C_);                 // t = 1
    const float4* __restrict__ wr = reinterpret_cast<const float4*>(
        W + (size_t)(d0 + row) * C_);

    float s = 0.f;
    // 256 float4 per row / 8 subs = 32 float4 per thread
    #pragma unroll
    for (int i = 0; i < 32; ++i) {
        const int k = sub + (i << 3);
        float4 a = xr[k];
        float4 w = wr[k];
        s += a.x * w.x + a.y * w.y + a.z * w.z + a.w * w.w;
    }
    // reduce the 8 sub-partials (lanes sub=0..7 are adjacent within a wave)
    s += __shfl_xor(s, 1, 64);
    s += __shfl_xor(s, 2, 64);
    s += __shfl_xor(s, 4, 64);
    if (sub == 0) v_s[row] = s + bias[d0 + row];
    __syncthreads();

    // ---- Phase 2: broadcast v_s[0..31] to all T rows ----
    // thread: t_sub = tid>>3 (0..31), d4 = tid&7 (8 float4 = 32 floats)
    const int t_sub = tid >> 3;
    const int d4    = tid & 7;
    const float4 val = reinterpret_cast<const float4*>(v_s)[d4];

    // out as float4: index = (b*T + t)*256 + d0/4 + d4 ; t = t_sub + 32*k
    float4* __restrict__ out4 = reinterpret_cast<float4*>(out);
    size_t idx = ((size_t)b << 19) + ((size_t)t_sub << 8) + (d0 >> 2) + d4;
    #pragma unroll 8
    for (int k = 0; k < 64; ++k) {       // t advances by 32 -> idx += 32*256
        out4[idx] = val;
        idx += 8192;
    }
}

extern "C" void kernel_launch(void* const* d_in, const int* in_sizes, int n_in,
                              void* d_out, int out_size, void* d_ws, size_t ws_size,
                              hipStream_t stream) {
    const float* x    = (const float*)d_in[0];
    const float* W    = (const float*)d_in[1];
    const float* bias = (const float*)d_in[2];
    float* out = (float*)d_out;

    fused_target_attn<<<256, 256, 0, stream>>>(x, W, bias, out);
}